// Round 13
// baseline (426.098 us; speedup 1.0000x reference)
//
#include <hip/hip_runtime.h>
#include <math.h>

// RationalQuadraticSpline: fused MLP (64->64->128->1600) + RQ spline.
// R12: R10 structure (lane=row, wave-uniform weights via s_load, transposed
// LDS, conflict-free). GEMM3 processes 2 features per pass: per k one
// ds_read feeds 50 FMAs (2x latency amortization vs R10's 25). Plain scalar
// fmaf (pk_fma is rate-neutral on CDNA4 -- fp32 peak = 1 fma/lane/cyc).
// Numerics: ascending-k fmaf chain per output, bitwise = R10 (absmax 0.125).

namespace {

constexpr int NTHR = 512;
constexpr int ROWS = 64;
constexpr float TBOUND = 3.0f;

// ---- pack W3 [128][1600] -> W3f [64][128][28]: f-major, k-contiguous ----
__global__ __launch_bounds__(256) void pack_w3(const float* __restrict__ W3,
                                               float* __restrict__ W3f) {
  int idx = blockIdx.x * 256 + threadIdx.x;   // 64*128*25 = 204800
  int f = idx / 3200;
  int rem = idx - f * 3200;
  int k = rem / 25;
  int p = rem - k * 25;
  W3f[(size_t)(f * 128 + k) * 28 + p] = W3[(size_t)k * 1600 + f * 25 + p];
}

__global__ __launch_bounds__(NTHR, 3) void rqs_fused(
    const float* __restrict__ x, const float* __restrict__ W1,
    const float* __restrict__ b1, const float* __restrict__ W2,
    const float* __restrict__ b2, const float* __restrict__ W3f,
    const float* __restrict__ b3, float* __restrict__ out,
    float* __restrict__ ldet) {
  __shared__ float xsT[64 * 65];   // [c][r]; y written back in place
  __shared__ float buf[128 * 65];  // h1T ([64][65]) then h2T ([128][65])
  __shared__ float ldp[8 * 64];    // per-wave ldet partials

  const int t = threadIdx.x;
  const int lane = t & 63;
  const int wv = __builtin_amdgcn_readfirstlane(t >> 6);  // wave id, SGPR
  const int row0 = blockIdx.x * ROWS;

  // ---- load x -> xsT (coalesced global, conflict-free LDS) ----
  for (int i = t; i < 64 * 64; i += NTHR) {
    int r = i >> 6, c = i & 63;
    xsT[c * 65 + r] = x[(size_t)(row0 + r) * 64 + c];
  }
  __syncthreads();

  // ---- GEMM1: h1 = relu(x @ W1 + b1); wave -> 8 cols, lane -> row ----
  {
    float acc[8];
#pragma unroll
    for (int j = 0; j < 8; ++j) acc[j] = 0.f;
    const float* w1base = W1 + wv * 8;   // uniform
#pragma unroll 4
    for (int k = 0; k < 64; ++k) {
      float xk = xsT[k * 65 + lane];
      const float* wr = w1base + k * 64;  // uniform -> s_load
#pragma unroll
      for (int j = 0; j < 8; ++j) acc[j] = fmaf(xk, wr[j], acc[j]);
    }
    const float* b1p = b1 + wv * 8;
#pragma unroll
    for (int j = 0; j < 8; ++j)
      buf[(wv * 8 + j) * 65 + lane] = fmaxf(acc[j] + b1p[j], 0.f);
  }
  __syncthreads();

  // ---- GEMM2: h2 = relu(h1 @ W2 + b2); wave -> 16 cols, lane -> row ----
  // h2 to registers; written over h1's buffer after the barrier.
  float h2r[16];
  {
    float acc[16];
#pragma unroll
    for (int j = 0; j < 16; ++j) acc[j] = 0.f;
    const float* w2base = W2 + wv * 16;  // uniform
#pragma unroll 2
    for (int k = 0; k < 64; ++k) {
      float hk = buf[k * 65 + lane];
      const float* wr = w2base + k * 128;  // uniform -> s_load
#pragma unroll
      for (int j = 0; j < 16; ++j) acc[j] = fmaf(hk, wr[j], acc[j]);
    }
    const float* b2p = b2 + wv * 16;
#pragma unroll
    for (int j = 0; j < 16; ++j)
      h2r[j] = fmaxf(acc[j] + b2p[j], 0.f);
  }
  __syncthreads();   // all h1 reads done; buf becomes h2T [128][65]
#pragma unroll
  for (int j = 0; j < 16; ++j)
    buf[(wv * 16 + j) * 65 + lane] = h2r[j];
  __syncthreads();

  // ---- GEMM3 + spline: wave -> features 8w..8w+7, 2 per pass; lane -> row ----
  float ldacc = 0.f;

  auto do_spline = [&](float* acc, int f) {
    const float* b3p = b3 + f * 25;  // uniform
#pragma unroll
    for (int p = 0; p < 25; ++p) acc[p] += b3p[p];  // params done
    const float xv = xsT[f * 65 + lane];

    float m = acc[0];
#pragma unroll
    for (int q = 1; q < 8; ++q) m = fmaxf(m, acc[q]);
    float sum = 0.f;
#pragma unroll
    for (int q = 0; q < 8; ++q) { acc[q] = __expf(acc[q] - m); sum += acc[q]; }
    float sc = 5.952f / sum;
#pragma unroll
    for (int q = 0; q < 8; ++q) acc[q] = acc[q] * sc + 0.001f;
    m = acc[8];
#pragma unroll
    for (int q = 1; q < 8; ++q) m = fmaxf(m, acc[8 + q]);
    sum = 0.f;
#pragma unroll
    for (int q = 0; q < 8; ++q) { acc[8 + q] = __expf(acc[8 + q] - m); sum += acc[8 + q]; }
    sc = 5.952f / sum;
#pragma unroll
    for (int q = 0; q < 8; ++q) acc[8 + q] = acc[8 + q] * sc + 0.001f;
#pragma unroll
    for (int q = 0; q < 9; ++q) {
      float v = acc[16 + q];
      acc[16 + q] = fmaxf(v, 0.f) + __logf(1.f + __expf(-fabsf(v))) + 0.001f;
    }

    const bool inside = (xv >= -TBOUND) && (xv <= TBOUND);
    const float xc = fminf(fmaxf(xv, -TBOUND), TBOUND);

    float cw = -TBOUND + acc[0];
    float chh = -TBOUND + acc[8];
    float cwk = -TBOUND, chk = -TBOUND;
    float wk = acc[0], hks = acc[8], dk = acc[16], dk1 = acc[17];
#pragma unroll
    for (int q = 1; q < 8; ++q) {
      bool g = (cw <= xc);
      cwk = g ? cw : cwk;
      chk = g ? chh : chk;
      wk = g ? acc[q] : wk;
      hks = g ? acc[8 + q] : hks;
      dk = g ? acc[16 + q] : dk;
      dk1 = g ? acc[17 + q] : dk1;
      cw += acc[q];
      chh += acc[8 + q];
    }

    float th = (xc - cwk) / wk;
    float om = 1.f - th;
    float th2 = th * th, thom = th * om, om2 = om * om;
    float num = hks * (dk * th2 + dk1 * thom);
    float den = dk * th2 + 2.f * dk1 * thom + dk1 * om2;
    float yv = chk + num / den;
    float dn = dk1 * th2 + 2.f * dk * thom + dk * om2;
    float ld = 2.f * __logf(dn) - 2.f * __logf(den) + __logf(hks) - __logf(wk);

    xsT[f * 65 + lane] = inside ? yv : xv;   // y in place (own slot)
    ldacc += inside ? ld : 0.f;
  };

#pragma unroll 1
  for (int pr = 0; pr < 4; ++pr) {
    const int f0 = wv * 8 + pr * 2;                   // uniform
    const float* wfA = W3f + (size_t)f0 * (128 * 28); // uniform
    const float* wfB = wfA + 128 * 28;                // uniform
    float accA[25], accB[25];
#pragma unroll
    for (int p = 0; p < 25; ++p) { accA[p] = 0.f; accB[p] = 0.f; }
#pragma unroll 2
    for (int k = 0; k < 128; ++k) {
      float hk = buf[k * 65 + lane];
      const float* wkA = wfA + k * 28;  // uniform -> s_load
      const float* wkB = wfB + k * 28;  // uniform -> s_load
#pragma unroll
      for (int p = 0; p < 25; ++p) {
        accA[p] = fmaf(hk, wkA[p], accA[p]);
        accB[p] = fmaf(hk, wkB[p], accB[p]);
      }
    }
    do_spline(accA, f0);      // ascending f order preserved (bitwise ldacc)
    do_spline(accB, f0 + 1);
  }

  ldp[wv * 64 + lane] = ldacc;
  __syncthreads();

  // ---- ldet: sum 8 wave-partials per row (wave-ascending = f-ascending) ----
  if (t < 64) {
    float s2 = 0.f;
#pragma unroll
    for (int w = 0; w < 8; ++w) s2 += ldp[w * 64 + t];
    ldet[row0 + t] = s2;
  }

  // ---- epilogue: coalesced y writes ----
  for (int i = t; i < 64 * 64; i += NTHR) {
    int r = i >> 6, c = i & 63;
    out[(size_t)(row0 + r) * 64 + c] = xsT[c * 65 + r];
  }
}

}  // namespace

extern "C" void kernel_launch(void* const* d_in, const int* in_sizes, int n_in,
                              void* d_out, int out_size, void* d_ws, size_t ws_size,
                              hipStream_t stream) {
  const float* x = (const float*)d_in[0];
  const float* W1 = (const float*)d_in[1];
  const float* b1 = (const float*)d_in[2];
  const float* W2 = (const float*)d_in[3];
  const float* b2 = (const float*)d_in[4];
  const float* W3 = (const float*)d_in[5];
  const float* b3 = (const float*)d_in[6];
  float* out = (float*)d_out;
  float* ldet = out + (size_t)65536 * 64;
  float* W3f = (float*)d_ws;   // 64*128*28*4 = 917504 B

  pack_w3<<<dim3(800), dim3(256), 0, stream>>>(W3, W3f);
  rqs_fused<<<dim3(65536 / ROWS), dim3(NTHR), 0, stream>>>(
      x, W1, b1, W2, b2, W3f, b3, out, ldet);
}

// Round 14
// 394.488 us; speedup vs baseline: 1.0801x; 1.0801x over previous
//
#include <hip/hip_runtime.h>
#include <math.h>

// RationalQuadraticSpline: fused MLP (64->64->128->1600) + RQ spline.
// R13: R12's 2-features-per-pass (50 FMA per ds_read, lowest VALU-op count)
// but with the pair's weights packed INTERLEAVED in ONE stream
// (W3p2[pair][k][52]: f's 25 then f+1's 25). Single sequential s_load stream
// restores prefetchability that R12's dual streams broke (2x28 live + 2x28
// prefetch = 112 SGPR = cap -> no double buffering -> latency exposed).
// Numerics: ascending-k fmaf chain per output, bitwise = R10 (absmax 0.125).

namespace {

constexpr int NTHR = 512;
constexpr int ROWS = 64;
constexpr float TBOUND = 3.0f;

// ---- pack W3 [128][1600] -> W3p2 [32][128][52]: pair-major, k-contiguous,
// within k: f0's p0..24 then f1's p0..24 (2 pad) ----
__global__ __launch_bounds__(256) void pack_w3(const float* __restrict__ W3,
                                               float* __restrict__ W3p2) {
  int idx = blockIdx.x * 256 + threadIdx.x;   // 64*128*25 = 204800
  int f = idx / 3200;
  int rem = idx - f * 3200;
  int k = rem / 25;
  int p = rem - k * 25;
  W3p2[(size_t)((f >> 1) * 128 + k) * 52 + (f & 1) * 25 + p] =
      W3[(size_t)k * 1600 + f * 25 + p];
}

__global__ __launch_bounds__(NTHR, 3) void rqs_fused(
    const float* __restrict__ x, const float* __restrict__ W1,
    const float* __restrict__ b1, const float* __restrict__ W2,
    const float* __restrict__ b2, const float* __restrict__ W3p2,
    const float* __restrict__ b3, float* __restrict__ out,
    float* __restrict__ ldet) {
  __shared__ float xsT[64 * 65];   // [c][r]; y written back in place
  __shared__ float buf[128 * 65];  // h1T ([64][65]) then h2T ([128][65])
  __shared__ float ldp[8 * 64];    // per-wave ldet partials

  const int t = threadIdx.x;
  const int lane = t & 63;
  const int wv = __builtin_amdgcn_readfirstlane(t >> 6);  // wave id, SGPR
  const int row0 = blockIdx.x * ROWS;

  // ---- load x -> xsT (coalesced global, conflict-free LDS) ----
  for (int i = t; i < 64 * 64; i += NTHR) {
    int r = i >> 6, c = i & 63;
    xsT[c * 65 + r] = x[(size_t)(row0 + r) * 64 + c];
  }
  __syncthreads();

  // ---- GEMM1: h1 = relu(x @ W1 + b1); wave -> 8 cols, lane -> row ----
  {
    float acc[8];
#pragma unroll
    for (int j = 0; j < 8; ++j) acc[j] = 0.f;
    const float* w1base = W1 + wv * 8;   // uniform
#pragma unroll 4
    for (int k = 0; k < 64; ++k) {
      float xk = xsT[k * 65 + lane];
      const float* wr = w1base + k * 64;  // uniform -> s_load
#pragma unroll
      for (int j = 0; j < 8; ++j) acc[j] = fmaf(xk, wr[j], acc[j]);
    }
    const float* b1p = b1 + wv * 8;
#pragma unroll
    for (int j = 0; j < 8; ++j)
      buf[(wv * 8 + j) * 65 + lane] = fmaxf(acc[j] + b1p[j], 0.f);
  }
  __syncthreads();

  // ---- GEMM2: h2 = relu(h1 @ W2 + b2); wave -> 16 cols, lane -> row ----
  // h2 to registers; written over h1's buffer after the barrier.
  float h2r[16];
  {
    float acc[16];
#pragma unroll
    for (int j = 0; j < 16; ++j) acc[j] = 0.f;
    const float* w2base = W2 + wv * 16;  // uniform
#pragma unroll 2
    for (int k = 0; k < 64; ++k) {
      float hk = buf[k * 65 + lane];
      const float* wr = w2base + k * 128;  // uniform -> s_load
#pragma unroll
      for (int j = 0; j < 16; ++j) acc[j] = fmaf(hk, wr[j], acc[j]);
    }
    const float* b2p = b2 + wv * 16;
#pragma unroll
    for (int j = 0; j < 16; ++j)
      h2r[j] = fmaxf(acc[j] + b2p[j], 0.f);
  }
  __syncthreads();   // all h1 reads done; buf becomes h2T [128][65]
#pragma unroll
  for (int j = 0; j < 16; ++j)
    buf[(wv * 16 + j) * 65 + lane] = h2r[j];
  __syncthreads();

  // ---- GEMM3 + spline: wave -> features 8w..8w+7, 2 per pass; lane -> row ----
  float ldacc = 0.f;

  auto do_spline = [&](float* acc, int f) {
    const float* b3p = b3 + f * 25;  // uniform
#pragma unroll
    for (int p = 0; p < 25; ++p) acc[p] += b3p[p];  // params done
    const float xv = xsT[f * 65 + lane];

    float m = acc[0];
#pragma unroll
    for (int q = 1; q < 8; ++q) m = fmaxf(m, acc[q]);
    float sum = 0.f;
#pragma unroll
    for (int q = 0; q < 8; ++q) { acc[q] = __expf(acc[q] - m); sum += acc[q]; }
    float sc = 5.952f / sum;
#pragma unroll
    for (int q = 0; q < 8; ++q) acc[q] = acc[q] * sc + 0.001f;
    m = acc[8];
#pragma unroll
    for (int q = 1; q < 8; ++q) m = fmaxf(m, acc[8 + q]);
    sum = 0.f;
#pragma unroll
    for (int q = 0; q < 8; ++q) { acc[8 + q] = __expf(acc[8 + q] - m); sum += acc[8 + q]; }
    sc = 5.952f / sum;
#pragma unroll
    for (int q = 0; q < 8; ++q) acc[8 + q] = acc[8 + q] * sc + 0.001f;
#pragma unroll
    for (int q = 0; q < 9; ++q) {
      float v = acc[16 + q];
      acc[16 + q] = fmaxf(v, 0.f) + __logf(1.f + __expf(-fabsf(v))) + 0.001f;
    }

    const bool inside = (xv >= -TBOUND) && (xv <= TBOUND);
    const float xc = fminf(fmaxf(xv, -TBOUND), TBOUND);

    float cw = -TBOUND + acc[0];
    float chh = -TBOUND + acc[8];
    float cwk = -TBOUND, chk = -TBOUND;
    float wk = acc[0], hks = acc[8], dk = acc[16], dk1 = acc[17];
#pragma unroll
    for (int q = 1; q < 8; ++q) {
      bool g = (cw <= xc);
      cwk = g ? cw : cwk;
      chk = g ? chh : chk;
      wk = g ? acc[q] : wk;
      hks = g ? acc[8 + q] : hks;
      dk = g ? acc[16 + q] : dk;
      dk1 = g ? acc[17 + q] : dk1;
      cw += acc[q];
      chh += acc[8 + q];
    }

    float th = (xc - cwk) / wk;
    float om = 1.f - th;
    float th2 = th * th, thom = th * om, om2 = om * om;
    float num = hks * (dk * th2 + dk1 * thom);
    float den = dk * th2 + 2.f * dk1 * thom + dk1 * om2;
    float yv = chk + num / den;
    float dn = dk1 * th2 + 2.f * dk * thom + dk * om2;
    float ld = 2.f * __logf(dn) - 2.f * __logf(den) + __logf(hks) - __logf(wk);

    xsT[f * 65 + lane] = inside ? yv : xv;   // y in place (own slot)
    ldacc += inside ? ld : 0.f;
  };

#pragma unroll 1
  for (int pr = 0; pr < 4; ++pr) {
    const int pair = wv * 4 + pr;                      // uniform
    const float* wp = W3p2 + (size_t)pair * (128 * 52);  // uniform, one stream
    float accA[25], accB[25];
#pragma unroll
    for (int p = 0; p < 25; ++p) { accA[p] = 0.f; accB[p] = 0.f; }
#pragma unroll 2
    for (int k = 0; k < 128; ++k) {
      float hk = buf[k * 65 + lane];
      const float* wk = wp + k * 52;  // uniform -> contiguous 200B s_load run
#pragma unroll
      for (int p = 0; p < 25; ++p) {
        accA[p] = fmaf(hk, wk[p], accA[p]);
        accB[p] = fmaf(hk, wk[25 + p], accB[p]);
      }
    }
    do_spline(accA, wv * 8 + pr * 2);      // ascending f order -> bitwise ldacc
    do_spline(accB, wv * 8 + pr * 2 + 1);
  }

  ldp[wv * 64 + lane] = ldacc;
  __syncthreads();

  // ---- ldet: sum 8 wave-partials per row (wave-ascending = f-ascending) ----
  if (t < 64) {
    float s2 = 0.f;
#pragma unroll
    for (int w = 0; w < 8; ++w) s2 += ldp[w * 64 + t];
    ldet[row0 + t] = s2;
  }

  // ---- epilogue: coalesced y writes ----
  for (int i = t; i < 64 * 64; i += NTHR) {
    int r = i >> 6, c = i & 63;
    out[(size_t)(row0 + r) * 64 + c] = xsT[c * 65 + r];
  }
}

}  // namespace

extern "C" void kernel_launch(void* const* d_in, const int* in_sizes, int n_in,
                              void* d_out, int out_size, void* d_ws, size_t ws_size,
                              hipStream_t stream) {
  const float* x = (const float*)d_in[0];
  const float* W1 = (const float*)d_in[1];
  const float* b1 = (const float*)d_in[2];
  const float* W2 = (const float*)d_in[3];
  const float* b2 = (const float*)d_in[4];
  const float* W3 = (const float*)d_in[5];
  const float* b3 = (const float*)d_in[6];
  float* out = (float*)d_out;
  float* ldet = out + (size_t)65536 * 64;
  float* W3p2 = (float*)d_ws;   // 32*128*52*4 = 851968 B

  pack_w3<<<dim3(800), dim3(256), 0, stream>>>(W3, W3p2);
  rqs_fused<<<dim3(65536 / ROWS), dim3(NTHR), 0, stream>>>(
      x, W1, b1, W2, b2, W3p2, b3, out, ldet);
}